// Round 1
// baseline (366.945 us; speedup 1.0000x reference)
//
#include <hip/hip_runtime.h>
#include <cstdint>
#include <cstddef>

// ---------------------------------------------------------------------------
// QuantizedLinear: out[b][o] = sum_k x[b][k] * ((qw[o][k]+32768)*scale + w_min)
//                              + (qb[o]+32768)*bias_scale + b_min
// B=8192, IN=4096, OUT=4096.  x fp32, qw/qb int32, out fp32.
// Strategy: dequant W and x to bf16 in workspace, then m97-style 128x128
// MFMA GEMM (16x16x32 bf16, global_load_lds width=16, linear LDS).
// ---------------------------------------------------------------------------

#define B_DIM  8192
#define IN_DIM 4096
#define OUT_DIM 4096

typedef short    bf16x8 __attribute__((ext_vector_type(8)));
typedef float    f32x4  __attribute__((ext_vector_type(4)));
typedef uint16_t u16x8  __attribute__((ext_vector_type(8)));

constexpr int BM = 128, BN = 128, BK = 32;

// round-to-nearest-even fp32 -> bf16 (inputs are finite)
__device__ __forceinline__ uint16_t f2bf(float f) {
  uint32_t u = __builtin_bit_cast(uint32_t, f);
  u += 0x7FFFu + ((u >> 16) & 1u);
  return (uint16_t)(u >> 16);
}

__device__ __forceinline__ void gload_lds16(const void* g, void* l) {
  __builtin_amdgcn_global_load_lds(
      (const __attribute__((address_space(1))) unsigned int*)g,
      (__attribute__((address_space(3))) unsigned int*)l,
      16, 0, 0);
}

// ---------------- prologue: conversions ----------------

// x fp32 -> bf16, 8 elems/thread
__global__ void cvt_x_kernel(const float* __restrict__ x,
                             uint16_t* __restrict__ o) {
  size_t i = (size_t)blockIdx.x * blockDim.x + threadIdx.x;  // 8 elems each
  const float4* xv = (const float4*)x;
  float4 a = xv[i * 2], b = xv[i * 2 + 1];
  u16x8 r;
  r[0] = f2bf(a.x); r[1] = f2bf(a.y); r[2] = f2bf(a.z); r[3] = f2bf(a.w);
  r[4] = f2bf(b.x); r[5] = f2bf(b.y); r[6] = f2bf(b.z); r[7] = f2bf(b.w);
  ((u16x8*)o)[i] = r;
}

// qw int32 -> dequant bf16, 8 elems/thread
__global__ void cvt_w_kernel(const int* __restrict__ q,
                             uint16_t* __restrict__ o,
                             const float* __restrict__ sp,
                             const float* __restrict__ wminp) {
  size_t i = (size_t)blockIdx.x * blockDim.x + threadIdx.x;  // 8 elems each
  float s = *sp, wmin = *wminp;
  const int4* qv = (const int4*)q;
  int4 a = qv[i * 2], b = qv[i * 2 + 1];
  u16x8 r;
  r[0] = f2bf(fmaf((float)a.x + 32768.0f, s, wmin));
  r[1] = f2bf(fmaf((float)a.y + 32768.0f, s, wmin));
  r[2] = f2bf(fmaf((float)a.z + 32768.0f, s, wmin));
  r[3] = f2bf(fmaf((float)a.w + 32768.0f, s, wmin));
  r[4] = f2bf(fmaf((float)b.x + 32768.0f, s, wmin));
  r[5] = f2bf(fmaf((float)b.y + 32768.0f, s, wmin));
  r[6] = f2bf(fmaf((float)b.z + 32768.0f, s, wmin));
  r[7] = f2bf(fmaf((float)b.w + 32768.0f, s, wmin));
  ((u16x8*)o)[i] = r;
}

__global__ void cvt_bias_kernel(const int* __restrict__ qb,
                                float* __restrict__ o,
                                const float* __restrict__ bsp,
                                const float* __restrict__ bminp) {
  int i = blockIdx.x * blockDim.x + threadIdx.x;
  if (i < OUT_DIM)
    o[i] = fmaf((float)qb[i] + 32768.0f, *bsp, *bminp);
}

// ---------------- main GEMM (m97 structure) ----------------
// A = Xbf16 [M=8192, K=4096] row-major; Bw = Wbf16 [N=4096, K=4096] row-major
// (B^T layout, NT GEMM). 4 waves, 2x2 wave grid, each wave: 64x64 = 4x4
// fragments of 16x16, K-step 32.

__global__ __launch_bounds__(256) void gemm_bt_kernel(
    const uint16_t* __restrict__ A, const uint16_t* __restrict__ Bw,
    const float* __restrict__ bias, float* __restrict__ C) {
  __shared__ bf16x8 As[BM * BK / 8];  // 8 KiB, linear [128][32] bf16
  __shared__ bf16x8 Bs[BM * BK / 8];  // 8 KiB

  const int tid  = threadIdx.x;
  const int wave = tid >> 6;
  const int lane = tid & 63;
  const int m0 = blockIdx.y * BM;
  const int n0 = blockIdx.x * BN;
  const int wr = wave >> 1, wc = wave & 1;
  const int lrow = lane & 15, kb = lane >> 4;

  f32x4 acc[4][4];
#pragma unroll
  for (int i = 0; i < 4; ++i)
#pragma unroll
    for (int j = 0; j < 4; ++j) acc[i][j] = (f32x4){0.f, 0.f, 0.f, 0.f};

  const uint16_t* aBase = A  + (size_t)m0 * IN_DIM;
  const uint16_t* bBase = Bw + (size_t)n0 * IN_DIM;

  for (int k0 = 0; k0 < IN_DIM; k0 += BK) {
    __syncthreads();  // all waves done reading LDS from previous tile
#pragma unroll
    for (int c = 0; c < 2; ++c) {
      int loff = (c * 4 + wave) * 1024;   // wave-uniform LDS byte offset
      int lin  = loff + lane * 16;        // this lane's byte pos in tile
      int row  = lin >> 6;                // 64 B per tile row
      int kel  = (lin & 63) >> 1;         // bf16 element within row
      gload_lds16(aBase + (size_t)row * IN_DIM + k0 + kel, (char*)As + loff);
      gload_lds16(bBase + (size_t)row * IN_DIM + k0 + kel, (char*)Bs + loff);
    }
    __syncthreads();  // compiler emits vmcnt(0) drain before barrier

    bf16x8 af[4], bfr[4];
#pragma unroll
    for (int mi = 0; mi < 4; ++mi)
      af[mi] = As[(wr * 64 + mi * 16 + lrow) * 4 + kb];
#pragma unroll
    for (int ni = 0; ni < 4; ++ni)
      bfr[ni] = Bs[(wc * 64 + ni * 16 + lrow) * 4 + kb];
#pragma unroll
    for (int mi = 0; mi < 4; ++mi)
#pragma unroll
      for (int ni = 0; ni < 4; ++ni)
        acc[mi][ni] = __builtin_amdgcn_mfma_f32_16x16x32_bf16(
            af[mi], bfr[ni], acc[mi][ni], 0, 0, 0);
  }

  // epilogue: C/D layout col = lane&15, row = (lane>>4)*4 + j
  const int r4 = (lane >> 4) * 4;
  const int cc = lane & 15;
#pragma unroll
  for (int ni = 0; ni < 4; ++ni) {
    int col = n0 + wc * 64 + ni * 16 + cc;
    float bv = bias[col];
#pragma unroll
    for (int mi = 0; mi < 4; ++mi) {
      int rowb = m0 + wr * 64 + mi * 16 + r4;
#pragma unroll
      for (int j = 0; j < 4; ++j)
        C[(size_t)(rowb + j) * OUT_DIM + col] = acc[mi][ni][j] + bv;
    }
  }
}

// ---------------- naive fallback (only if ws too small) ----------------
__global__ void naive_ql_kernel(const float* __restrict__ x,
                                const int* __restrict__ qw,
                                const int* __restrict__ qb,
                                const float* sp, const float* wminp,
                                const float* bsp, const float* bminp,
                                float* __restrict__ out) {
  int o = blockIdx.x * blockDim.x + threadIdx.x;
  int b = blockIdx.y;
  float s = *sp, wmin = *wminp;
  const float* xr = x + (size_t)b * IN_DIM;
  const int* wrow = qw + (size_t)o * IN_DIM;
  float acc = 0.f;
  for (int k = 0; k < IN_DIM; ++k)
    acc += xr[k] * fmaf((float)wrow[k] + 32768.0f, s, wmin);
  out[(size_t)b * OUT_DIM + o] =
      acc + fmaf((float)qb[o] + 32768.0f, *bsp, *bminp);
}

// ---------------- launch ----------------
extern "C" void kernel_launch(void* const* d_in, const int* in_sizes, int n_in,
                              void* d_out, int out_size, void* d_ws,
                              size_t ws_size, hipStream_t stream) {
  const float* x      = (const float*)d_in[0];
  const int*   qw     = (const int*)d_in[1];
  const int*   qb     = (const int*)d_in[2];
  const float* scale  = (const float*)d_in[3];
  const float* wmin   = (const float*)d_in[4];
  const float* bscale = (const float*)d_in[5];
  const float* bmin   = (const float*)d_in[6];
  float* out = (float*)d_out;

  const size_t xb_bytes = (size_t)B_DIM * IN_DIM * 2;      // 64 MiB
  const size_t wb_bytes = (size_t)OUT_DIM * IN_DIM * 2;    // 32 MiB
  const size_t bias_bytes = (size_t)OUT_DIM * 4;

  if (ws_size < xb_bytes + wb_bytes + bias_bytes) {
    // emergency correct path (slow) — signals ws_size is too small
    naive_ql_kernel<<<dim3(OUT_DIM / 256, B_DIM), 256, 0, stream>>>(
        x, qw, qb, scale, wmin, bscale, bmin, out);
    return;
  }

  uint16_t* Xb    = (uint16_t*)d_ws;
  uint16_t* Wb    = (uint16_t*)((char*)d_ws + xb_bytes);
  float*    biasf = (float*)((char*)d_ws + xb_bytes + wb_bytes);

  // x: 33.5M elems / 8 per thread
  cvt_x_kernel<<<(B_DIM * (size_t)IN_DIM / 8 + 255) / 256, 256, 0, stream>>>(x, Xb);
  // w: 16.8M elems / 8 per thread
  cvt_w_kernel<<<(OUT_DIM * (size_t)IN_DIM / 8 + 255) / 256, 256, 0, stream>>>(
      qw, Wb, scale, wmin);
  cvt_bias_kernel<<<(OUT_DIM + 255) / 256, 256, 0, stream>>>(qb, biasf, bscale,
                                                             bmin);

  dim3 grid(OUT_DIM / BN, B_DIM / BM);  // (32, 64)
  gemm_bt_kernel<<<grid, 256, 0, stream>>>(Xb, Wb, biasf, out);
}